// Round 5
// baseline (213.276 us; speedup 1.0000x reference)
//
#include <hip/hip_runtime.h>
#include <math.h>

typedef _Float16 f16;
typedef f16 f16x2 __attribute__((ext_vector_type(2)));
typedef f16 f16x8 __attribute__((ext_vector_type(8)));
typedef f16 f16x4 __attribute__((ext_vector_type(4)));
typedef float f32x16 __attribute__((ext_vector_type(16)));

#define KEEP(x) asm volatile("" : "+v"(x))

// ws layout (f16 units):
//  mid W (w1,w2,w3) per-wave frags, single f16:
//    flat = (((l*2+fg)*8+ks)*2+ft)*512 + (32*g+ln)*8 + i
//  W0 frags at 49152 (2048 f16): ((fg*2+ft)*2+g)*256 + ln*8 + i (k<16, pad 0)
//  packed bias (f32) at f16-offset 53248: 512 floats
//  w4 f16 pairs at 54272: [o][128]: idx o*128+2j+p = w4[4j+2p+o]
#define WS_W0 49152
#define WS_BIAS 53248
#define WS_W4 54272

__global__ void zero_f32(float* __restrict__ p, int n) {
    int i = blockIdx.x * blockDim.x + threadIdx.x;
    if (i < n) p[i] = 0.0f;
}

__global__ void prep_weights(const float* __restrict__ w1, const float* __restrict__ w2,
                             const float* __restrict__ w3, const float* __restrict__ w0,
                             const float* __restrict__ b0, const float* __restrict__ b1,
                             const float* __restrict__ b2, const float* __restrict__ b3,
                             const float* __restrict__ w4, f16* __restrict__ ws) {
    int t = blockIdx.x * 256 + threadIdx.x;
    if (t < 49152) {
        int l = t >> 14;
        int r = t & 16383;
        int k = r >> 7, f = r & 127;
        const float* w = (l == 0) ? w1 : (l == 1) ? w2 : w3;
        float v = w[k * 128 + f];
        int fg = f >> 6, ft = (f >> 5) & 1, ln = f & 31;
        int ks = k >> 4, g = (k >> 3) & 1, i = k & 7;
        ws[(((l * 2 + fg) * 8 + ks) * 2 + ft) * 512 + (32 * g + ln) * 8 + i] = (f16)v;
    } else if (t < 51200) {
        int r = t - 49152;
        int k = r >> 7, f = r & 127;   // k 0..15
        float v = (k < 9) ? w0[k * 128 + f] : 0.0f;
        int fg = f >> 6, ft = (f >> 5) & 1, ln = f & 31;
        int g = (k >> 3) & 1, i = k & 7;
        ws[WS_W0 + ((fg * 2 + ft) * 2 + g) * 256 + ln * 8 + i] = (f16)v;
    } else if (t < 51712) {
        int b = t - 51200;             // 0..511
        int l = b >> 7, r = b & 127;
        int fg = r >> 6, ft = (r >> 5) & 1, g = (r >> 4) & 1, j = (r >> 2) & 3, m = r & 3;
        const float* bl = (l == 0) ? b0 : (l == 1) ? b1 : (l == 2) ? b2 : b3;
        ((float*)(ws + WS_BIAS))[b] = bl[64 * fg + 32 * ft + 8 * j + 4 * g + m];
    } else if (t < 51968) {
        int m = t - 51712;             // 0..255
        int o = m >> 7, r = m & 127;
        int j = r >> 1, p = r & 1;
        ws[WS_W4 + o * 128 + 2 * j + p] = (f16)w4[4 * j + 2 * p + o];
    }
}

__launch_bounds__(256, 4)
__global__ void gnn_mfma(const float* __restrict__ pos, const float* __restrict__ vel,
                         const float* __restrict__ a, const float* __restrict__ vnorm,
                         const float* __restrict__ b4,
                         const int* __restrict__ ei, const int* __restrict__ did,
                         const f16* __restrict__ ws, float* __restrict__ out,
                         int nNodes, int nEdges)
{
    __shared__ __align__(16) f16 A0[8192], A1[8192];   // 2 x 16 KB, 4-bit chunk-swizzle

    const int tid = threadIdx.x;
    const int lane = tid & 63;
    const int wid = tid >> 6;
    const int eg = wid & 1, fg = wid >> 1;
    const int g = lane >> 5, ln = lane & 31;
    const int el = 32 * eg + ln;
    const int e0 = blockIdx.x * 64;

    const f16x8* wsv = (const f16x8*)ws;
    const float* wsb = (const float*)(ws + WS_BIAS);

    // W frags for current mid layer — pinned resident via KEEP
    f16x8 W[16];
    #pragma unroll
    for (int ks = 0; ks < 8; ++ks)
        #pragma unroll
        for (int ft = 0; ft < 2; ++ft) {
            W[ks * 2 + ft] = wsv[(((0 * 2 + fg) * 8 + ks) * 2 + ft) * 64 + lane];
            KEEP(W[ks * 2 + ft]);
        }

    f16x8 w0f0 = wsv[WS_W0 / 8 + ((fg * 2 + 0) * 2 + g) * 32 + ln];
    f16x8 w0f1 = wsv[WS_W0 / 8 + ((fg * 2 + 1) * 2 + g) * 32 + ln];

    // ---- gather: 9 features, hi in chunks 0-1, lo in chunks 2-3 ----
    if (tid < 64) {
        int e = e0 + tid;
        int d = 0, s = 0;
        if (e < nEdges) { d = ei[e]; s = ei[nEdges + e]; }
        float2 pd = ((const float2*)pos)[d];
        float2 ps = ((const float2*)pos)[s];
        float2 vd = ((const float2*)vel)[d];
        float2 vs = ((const float2*)vel)[s];
        const float2* emb = (const float2*)(a + (size_t)did[0] * (size_t)nNodes * 2);
        float2 ae = emb[d];
        float invn = 1.0f / vnorm[0];
        float fx[9];
        fx[0] = (ps.x - pd.x) / 0.1f;
        fx[1] = (ps.y - pd.y) / 0.1f;
        fx[2] = sqrtf(fx[0] * fx[0] + fx[1] * fx[1]);
        fx[3] = vd.x * invn; fx[4] = vd.y * invn;
        fx[5] = vs.x * invn; fx[6] = vs.y * invn;
        fx[7] = ae.x; fx[8] = ae.y;
        f16x8 h0, l0, h1, l1;
        #pragma unroll
        for (int i = 0; i < 8; ++i) {
            f16 h = (f16)fx[i];
            h0[i] = h; l0[i] = (f16)(fx[i] - (float)h);
            h1[i] = (f16)0; l1[i] = (f16)0;
        }
        f16 h8 = (f16)fx[8];
        h1[0] = h8; l1[0] = (f16)(fx[8] - (float)h8);
        int er = tid;
        *(f16x8*)&A0[er * 128 + 8 * (0 ^ (er & 15))] = h0;
        *(f16x8*)&A0[er * 128 + 8 * (1 ^ (er & 15))] = h1;
        *(f16x8*)&A0[er * 128 + 8 * (2 ^ (er & 15))] = l0;
        *(f16x8*)&A0[er * 128 + 8 * (3 ^ (er & 15))] = l1;
    }
    __syncthreads();

    f32x16 acc0, acc1;

    auto bias_init = [&](int l) {
        #pragma unroll
        for (int ft = 0; ft < 2; ++ft) {
            const float* bp = wsb + ((l * 2 + fg) * 2 + ft) * 32 + g * 16;
            #pragma unroll
            for (int j = 0; j < 4; ++j) {
                float4 bv = *(const float4*)(bp + 4 * j);
                if (ft) { acc1[4*j] = bv.x; acc1[4*j+1] = bv.y; acc1[4*j+2] = bv.z; acc1[4*j+3] = bv.w; }
                else    { acc0[4*j] = bv.x; acc0[4*j+1] = bv.y; acc0[4*j+2] = bv.z; acc0[4*j+3] = bv.w; }
            }
        }
    };

    auto writeback = [&](f16* N) {
        #pragma unroll
        for (int ft = 0; ft < 2; ++ft)
            #pragma unroll
            for (int j = 0; j < 4; ++j) {
                f16x4 hv;
                #pragma unroll
                for (int m = 0; m < 4; ++m)
                    hv[m] = (f16)fmaxf((ft ? acc1 : acc0)[4 * j + m], 0.0f);
                int c = 8 * fg + 4 * ft + j;
                *(f16x4*)&N[el * 128 + 8 * (c ^ (el & 15)) + 4 * g] = hv;
            }
    };

    // ---- layer 0: K=16, input hi/lo ----
    bias_init(0);
    {
        f16x8 bhi = *(const f16x8*)&A0[el * 128 + 8 * (g ^ (el & 15))];
        f16x8 blo = *(const f16x8*)&A0[el * 128 + 8 * ((2 + g) ^ (el & 15))];
        acc0 = __builtin_amdgcn_mfma_f32_32x32x16_f16(w0f0, bhi, acc0, 0, 0, 0);
        acc1 = __builtin_amdgcn_mfma_f32_32x32x16_f16(w0f1, bhi, acc1, 0, 0, 0);
        acc0 = __builtin_amdgcn_mfma_f32_32x32x16_f16(w0f0, blo, acc0, 0, 0, 0);
        acc1 = __builtin_amdgcn_mfma_f32_32x32x16_f16(w0f1, blo, acc1, 0, 0, 0);
    }
    writeback(A1);
    __syncthreads();

    // ---- mid layers: K=128, W from regs, B single-f16 from LDS ----
    auto midlayer = [&](int l, const f16* S) {
        bias_init(l + 1);
        #pragma unroll
        for (int ks = 0; ks < 8; ++ks) {
            f16x8 b = *(const f16x8*)&S[el * 128 + 8 * ((2 * ks + g) ^ (el & 15))];
            acc0 = __builtin_amdgcn_mfma_f32_32x32x16_f16(W[ks * 2 + 0], b, acc0, 0, 0, 0);
            acc1 = __builtin_amdgcn_mfma_f32_32x32x16_f16(W[ks * 2 + 1], b, acc1, 0, 0, 0);
        }
    };

    midlayer(0, A1);                   // w1: A1 -> A0
    #pragma unroll
    for (int ks = 0; ks < 8; ++ks)     // prefetch w2 after last use of w1 frags
        #pragma unroll
        for (int ft = 0; ft < 2; ++ft) {
            W[ks * 2 + ft] = wsv[(((1 * 2 + fg) * 8 + ks) * 2 + ft) * 64 + lane];
            KEEP(W[ks * 2 + ft]);
        }
    writeback(A0);
    __syncthreads();

    midlayer(1, A0);                   // w2: A0 -> A1
    #pragma unroll
    for (int ks = 0; ks < 8; ++ks)     // prefetch w3
        #pragma unroll
        for (int ft = 0; ft < 2; ++ft) {
            W[ks * 2 + ft] = wsv[(((2 * 2 + fg) * 8 + ks) * 2 + ft) * 64 + lane];
            KEEP(W[ks * 2 + ft]);
        }
    writeback(A1);
    __syncthreads();

    midlayer(2, A1);                   // w3: A1 -> A0
    writeback(A0);
    __syncthreads();

    // ---- final layer 128 -> 2 via fdot2, atomic segment-sum ----
    {
        int e = tid >> 2, q = tid & 3;
        const f16x8* wp = (const f16x8*)(ws + WS_W4);
        float y0 = 0.0f, y1 = 0.0f;
        #pragma unroll
        for (int cc = 0; cc < 4; ++cc) {
            int c = 4 * q + cc;
            f16x8 hv = *(const f16x8*)&A0[e * 128 + 8 * (c ^ (e & 15))];
            f16x8 wv0 = wp[c];
            f16x8 wv1 = wp[16 + c];
            #pragma unroll
            for (int i = 0; i < 4; ++i) {
                f16x2 xa; xa[0] = hv[2*i]; xa[1] = hv[2*i+1];
                f16x2 wa; wa[0] = wv0[2*i]; wa[1] = wv0[2*i+1];
                f16x2 wb; wb[0] = wv1[2*i]; wb[1] = wv1[2*i+1];
                y0 = __builtin_amdgcn_fdot2(xa, wa, y0, false);
                y1 = __builtin_amdgcn_fdot2(xa, wb, y1, false);
            }
        }
        y0 += __shfl_xor(y0, 1); y0 += __shfl_xor(y0, 2);
        y1 += __shfl_xor(y1, 1); y1 += __shfl_xor(y1, 2);
        int eG = e0 + e;
        if (q == 0 && eG < nEdges) {
            int d = ei[eG];
            atomicAdd(&out[2 * d],     y0 + b4[0]);
            atomicAdd(&out[2 * d + 1], y1 + b4[1]);
        }
    }
}

extern "C" void kernel_launch(void* const* d_in, const int* in_sizes, int n_in,
                              void* d_out, int out_size, void* d_ws, size_t ws_size,
                              hipStream_t stream) {
    const float* pos   = (const float*)d_in[0];
    const float* vel   = (const float*)d_in[1];
    const float* a     = (const float*)d_in[2];
    const float* vnorm = (const float*)d_in[3];
    const float* w0    = (const float*)d_in[4];
    const float* b0    = (const float*)d_in[5];
    const float* w1    = (const float*)d_in[6];
    const float* b1    = (const float*)d_in[7];
    const float* w2    = (const float*)d_in[8];
    const float* b2    = (const float*)d_in[9];
    const float* w3    = (const float*)d_in[10];
    const float* b3    = (const float*)d_in[11];
    const float* w4    = (const float*)d_in[12];
    const float* b4    = (const float*)d_in[13];
    const int*   ei    = (const int*)d_in[14];
    const int*   did   = (const int*)d_in[15];
    float* out = (float*)d_out;
    f16* ws = (f16*)d_ws;

    int nEdges = in_sizes[14] / 2;   // 800000
    int nNodes = in_sizes[0] / 2;    // 50000

    hipLaunchKernelGGL(zero_f32, dim3((out_size + 255) / 256), dim3(256), 0, stream,
                       out, out_size);
    hipLaunchKernelGGL(prep_weights, dim3(203), dim3(256), 0, stream,
                       w1, w2, w3, w0, b0, b1, b2, b3, w4, ws);
    int ntiles = (nEdges + 63) / 64;
    hipLaunchKernelGGL(gnn_mfma, dim3(ntiles), dim3(256), 0, stream,
                       pos, vel, a, vnorm, b4, ei, did, ws, out,
                       nNodes, nEdges);
}